// Round 16
// baseline (127.938 us; speedup 1.0000x reference)
//
#include <hip/hip_runtime.h>

#define RANK  32
#define DIM   128
#define TROWS 64   // rows per wave-task = 4 MFMA tile-rows

// Round-16 = round 15 (126.1us) + NON-TEMPORAL C-stores. Single variable.
// Round-15 falsified the "prologue/tail exposure" theory (persistent loop
// bought ~1us). Issue accounting: ~3us/SIMD total — not issue-bound. The
// kernel runs at 4.2 TB/s effective vs fillBuffer's 6.8 on the same data:
// memory-system-side interference. Mechanism: the 410MB write-once output
// stream allocates through L2(32MB)/L3(256MB), evicting W1 (128MB — would
// otherwise be fully L3-resident). Evidence: FETCH 114MB vs ~78MB ideal =
// ~35MB of W1 re-fetch. NT stores (global_store nt) minimize allocation:
// W1 stays cached, gather latency drops, DRAM turnaround pressure drops.
// Layouts (m89/m162-verified, HW-confirmed rounds 12-15):
// A[m][k],B[k][n]: lane l elem e <-> m|n=l&15, k=4*(l>>4)+(e&3)+16*(e>>2).
// C: row=(l>>4)*4+reg, col=l&15.

typedef __attribute__((ext_vector_type(8))) short bf16x8;
typedef __attribute__((ext_vector_type(4))) float f32x4;

static __device__ __forceinline__ short f2bf(float f) {
  unsigned u = __float_as_uint(f);
  return (short)((u + 0x7FFFu + ((u >> 16) & 1u)) >> 16);  // RNE
}

__global__ __launch_bounds__(256)
__attribute__((amdgpu_waves_per_eu(4, 4)))
void lowrank_emb_kernel(
    const int* __restrict__ idx,
    const float* __restrict__ W1,
    const float* __restrict__ W2,
    float* __restrict__ out,
    int n_rows)
{
  const int lane       = threadIdx.x & 63;
  const int globalWave = blockIdx.x * 4 + (threadIdx.x >> 6);
  const int totalWaves = gridDim.x * 4;

  const int q   = lane >> 4;   // k-quad selector (0..3)
  const int mn  = lane & 15;   // row-of-A / col-of-B within tile
  const int nTasks  = (n_rows + TROWS - 1) / TROWS;
  const int lastIdx = n_rows - 1;

  int t = globalWave;
  if (t >= nTasks) return;

  // W2 B-fragments: lane l elem e holds bf16(W2[4q+(e&3)+16*(e>>2)][16t+mn]).
  // 32 VGPRs, pinned resident (round-1 lesson).
  bf16x8 bfrag[8];
#pragma unroll
  for (int tt = 0; tt < 8; ++tt) {
    bf16x8 v;
#pragma unroll
    for (int e = 0; e < 8; ++e) {
      const int k = 4 * q + (e & 3) + 16 * (e >> 2);
      v[e] = f2bf(W2[k * DIM + 16 * tt + mn]);
    }
    bfrag[tt] = v;
  }
#pragma unroll
  for (int tt = 0; tt < 8; ++tt) asm("" : "+v"(bfrag[tt]));

  auto gather = [&](int iv, float4* lo, float4* hi) {
    // Tile-row tr needs W1 row 16tr+mn, k-chunks [4q,+4) and [16+4q,+4).
    // 8 independent 16B loads; each W1 row fetched exactly once per task.
#pragma unroll
    for (int tr = 0; tr < 4; ++tr) {
      const int e = __shfl(iv, tr * 16 + mn, 64);
      const float* rp = W1 + (size_t)e * RANK + 4 * q;
      lo[tr] = *reinterpret_cast<const float4*>(rp);
      hi[tr] = *reinterpret_cast<const float4*>(rp + 16);
    }
  };

  // Prologue: idx + gathers for task t; idx prefetch for t+stride.
  float4 alo[4], ahi[4];
  {
    const int r = t * TROWS + lane;
    const int iv0 = idx[r < n_rows ? r : lastIdx];
    gather(iv0, alo, ahi);
  }
  int ivNext;
  {
    const int tn = t + totalWaves;
    const int r  = tn * TROWS + lane;
    ivNext = idx[(tn < nTasks && r < n_rows) ? r : lastIdx];
  }

  while (true) {
    // (1) Convert current task's gather to fragments (compiler inserts the
    // vmcnt wait here), freeing alo/ahi for the next task's loads.
    bf16x8 af[4];
#pragma unroll
    for (int tr = 0; tr < 4; ++tr) {
      bf16x8 v;
      v[0] = f2bf(alo[tr].x); v[1] = f2bf(alo[tr].y);
      v[2] = f2bf(alo[tr].z); v[3] = f2bf(alo[tr].w);
      v[4] = f2bf(ahi[tr].x); v[5] = f2bf(ahi[tr].y);
      v[6] = f2bf(ahi[tr].z); v[7] = f2bf(ahi[tr].w);
      af[tr] = v;
    }

    // (2) Issue NEXT task's gathers — they fly under this task's MFMA+stores.
    const int tn = t + totalWaves;
    if (tn < nTasks) gather(ivNext, alo, ahi);

    // (3) Prefetch idx two tasks ahead.
    {
      const int t2 = tn + totalWaves;
      const int r  = t2 * TROWS + lane;
      ivNext = idx[(t2 < nTasks && r < n_rows) ? r : lastIdx];
    }

    // (4) Compute + store current task. Stores are NON-TEMPORAL: output is
    // write-once; keep it out of L2/L3 so W1 stays cache-resident.
    const int rowBase = t * TROWS;
    const bool full = (rowBase + TROWS) <= n_rows;
#pragma unroll
    for (int tr = 0; tr < 4; ++tr) {
      f32x4 acc[8];
#pragma unroll
      for (int tc = 0; tc < 8; ++tc)
        acc[tc] = __builtin_amdgcn_mfma_f32_16x16x32_bf16(
            af[tr], bfrag[tc], (f32x4){0.f, 0.f, 0.f, 0.f}, 0, 0, 0);

      const int rb = rowBase + tr * 16 + q * 4;  // C: row=(l>>4)*4+reg
#pragma unroll
      for (int rr = 0; rr < 4; ++rr) {
        if (full || (rb + rr) < n_rows) {
          float* op = out + (size_t)(rb + rr) * DIM + mn;
#pragma unroll
          for (int tc = 0; tc < 8; ++tc)
            __builtin_nontemporal_store(acc[tc][rr], op + 16 * tc);
        }
      }
    }

    if (tn >= nTasks) break;
    t = tn;
  }
}

extern "C" void kernel_launch(void* const* d_in, const int* in_sizes, int n_in,
                              void* d_out, int out_size, void* d_ws, size_t ws_size,
                              hipStream_t stream) {
  const int*   idx = (const int*)d_in[0];   // [4096*200]
  const float* W1  = (const float*)d_in[1]; // [1e6, 32]
  const float* W2  = (const float*)d_in[2]; // [32, 128]
  float*       out = (float*)d_out;         // [4096*200, 128]
  const int n_rows = in_sizes[0];

  const int threads = 256;   // 4 waves/block
  const int blocks  = 1024;  // exactly resident (4 blocks/CU); persistent loop
  hipLaunchKernelGGL(lowrank_emb_kernel, dim3(blocks), dim3(threads), 0, stream,
                     idx, W1, W2, out, n_rows);
}